// Round 2
// baseline (309.144 us; speedup 1.0000x reference)
//
#include <hip/hip_runtime.h>
#include <hip/hip_bf16.h>

#define IN_FEATURES   4096
#define LOCAL_FEATURES  32
#define KERNEL_SIZE     64
#define FOLD_NUM      4096
#define BATCH          256

using bf16 = __hip_bfloat16;
typedef __attribute__((ext_vector_type(8))) short bf16x8;
typedef __attribute__((ext_vector_type(4))) float f32x4;

#define LDA 80  // padded LDS stride (bf16 elems): 160B, keeps 16B alignment for b128 reads
#define LDB 80

__global__ __launch_bounds__(256, 2)
void local_linear_kernel(const float* __restrict__ x,
                         const float* __restrict__ w,
                         const float* __restrict__ bias,
                         float* __restrict__ out)
{
    __shared__ bf16 As[BATCH * LDA];           // 40 KB: x window, [m][k]
    __shared__ bf16 Bs[LOCAL_FEATURES * LDB];  //  5 KB: weight transposed, [n][k]

    const int f    = blockIdx.x;
    const int t    = threadIdx.x;
    const int lane = t & 63;
    const int wid  = t >> 6;      // wave id 0..3

    // ---- stage x window into As (bf16), zero-pad past IN_FEATURES ----
    {
        const int col  = lane;             // k position 0..63
        const int gcol = f + col;
        const bool valid = (gcol < IN_FEATURES);
        const float* xp = x + gcol;        // per-lane base, row-strided
        #pragma unroll 8
        for (int i = 0; i < 64; ++i) {
            const int row = wid + i * 4;   // 0..255, coalesced 256B per wave
            float v = valid ? xp[(size_t)row * IN_FEATURES] : 0.0f;
            As[row * LDA + col] = __float2bfloat16(v);
        }
    }

    // ---- stage weight transposed into Bs[n][k] ----
    {
        const float* wf = w + (size_t)f * (KERNEL_SIZE * LOCAL_FEATURES);
        #pragma unroll
        for (int v4 = 0; v4 < 2; ++v4) {
            const int e0 = (t + v4 * 256) * 4;            // element index k*32+n
            const float4 val = *reinterpret_cast<const float4*>(wf + e0);
            const int k = e0 >> 5;
            const int n = e0 & 31;
            Bs[(n + 0) * LDB + k] = __float2bfloat16(val.x);
            Bs[(n + 1) * LDB + k] = __float2bfloat16(val.y);
            Bs[(n + 2) * LDB + k] = __float2bfloat16(val.z);
            Bs[(n + 3) * LDB + k] = __float2bfloat16(val.w);
        }
    }
    __syncthreads();

    // ---- MFMA: per wave M=64 (4 m-tiles), N=32 (2 n-tiles), K=64 (2 k-steps) ----
    f32x4 acc[4][2];
    #pragma unroll
    for (int mt = 0; mt < 4; ++mt)
        #pragma unroll
        for (int nt = 0; nt < 2; ++nt)
            acc[mt][nt] = (f32x4){0.f, 0.f, 0.f, 0.f};

    const int lrow = lane & 15;   // M-row (A) / N-col (B,D) within tile
    const int kgrp = lane >> 4;   // 0..3

    #pragma unroll
    for (int ks = 0; ks < 2; ++ks) {
        const int kbase = ks * 32 + kgrp * 8;
        bf16x8 bfrag[2], afrag[4];
        #pragma unroll
        for (int nt = 0; nt < 2; ++nt) {
            const int n = nt * 16 + lrow;
            bfrag[nt] = *reinterpret_cast<const bf16x8*>(&Bs[n * LDB + kbase]);
        }
        #pragma unroll
        for (int mt = 0; mt < 4; ++mt) {
            const int m = wid * 64 + mt * 16 + lrow;
            afrag[mt] = *reinterpret_cast<const bf16x8*>(&As[m * LDA + kbase]);
        }
        #pragma unroll
        for (int mt = 0; mt < 4; ++mt)
            #pragma unroll
            for (int nt = 0; nt < 2; ++nt)
                acc[mt][nt] = __builtin_amdgcn_mfma_f32_16x16x32_bf16(
                    afrag[mt], bfrag[nt], acc[mt][nt], 0, 0, 0);
    }

    // ---- epilogue: D[row=(lane>>4)*4+r][col=lane&15], add bias, store f32 ----
    float bv[2];
    bv[0] = bias[f * 32 + lrow];
    bv[1] = bias[f * 32 + 16 + lrow];

    #pragma unroll
    for (int mt = 0; mt < 4; ++mt) {
        #pragma unroll
        for (int nt = 0; nt < 2; ++nt) {
            const int n = nt * 16 + lrow;
            #pragma unroll
            for (int r = 0; r < 4; ++r) {
                const int b = wid * 64 + mt * 16 + kgrp * 4 + r;
                out[((size_t)b * FOLD_NUM + f) * 32 + n] = acc[mt][nt][r] + bv[nt];
            }
        }
    }
}

extern "C" void kernel_launch(void* const* d_in, const int* in_sizes, int n_in,
                              void* d_out, int out_size, void* d_ws, size_t ws_size,
                              hipStream_t stream) {
    const float* x    = (const float*)d_in[0];
    const float* wgt  = (const float*)d_in[1];
    const float* bias = (const float*)d_in[2];
    float* out        = (float*)d_out;
    local_linear_kernel<<<FOLD_NUM, 256, 0, stream>>>(x, wgt, bias, out);
}

// Round 4
// 203.049 us; speedup vs baseline: 1.5225x; 1.5225x over previous
//
#include <hip/hip_runtime.h>
#include <hip/hip_bf16.h>

#define IN_FEATURES   4096
#define LOCAL_FEATURES  32
#define KERNEL_SIZE     64
#define FOLD_NUM      4096
#define BATCH          256

// padded geometry for aligned loads
#define XROW 4192               // 4096 + 96 pad (bf16 elems), row stride 8384 B (16B-mult)
#define KPAD 96                 // K padded 64 -> 96 so slot base (f & ~7) keeps 16B alignment

using bf16 = __hip_bfloat16;
typedef __attribute__((ext_vector_type(8))) short bf16x8;
typedef __attribute__((ext_vector_type(4))) float f32x4;

static __device__ __forceinline__ short bfbits(float v) {
    __hip_bfloat16 h = __float2bfloat16(v);
    return *reinterpret_cast<short*>(&h);
}

// ---------- prepass A: x f32 [256][4096] -> bf16 [256][4192], zero pad ----------
__global__ void convert_pad_x(const float* __restrict__ x, bf16* __restrict__ xb) {
    const int u   = blockIdx.x * 256 + threadIdx.x;   // 134144 vec8 units = 256*524
    const int row = u / 524;
    const int c8  = (u - row * 524) * 8;
    bf16x8 o;
    if (c8 < 4096) {
        const float4 a = *reinterpret_cast<const float4*>(x + (size_t)row * 4096 + c8);
        const float4 b = *reinterpret_cast<const float4*>(x + (size_t)row * 4096 + c8 + 4);
        o[0] = bfbits(a.x); o[1] = bfbits(a.y); o[2] = bfbits(a.z); o[3] = bfbits(a.w);
        o[4] = bfbits(b.x); o[5] = bfbits(b.y); o[6] = bfbits(b.z); o[7] = bfbits(b.w);
    } else {
        o = (bf16x8){0,0,0,0,0,0,0,0};
    }
    *reinterpret_cast<bf16x8*>(xb + (size_t)row * XROW + c8) = o;
}

// ---------- prepass B: W f32 [f][64][32] -> bf16 ws_w[f][n=32][KPAD=96] -----------
// ws_w[f][n][kk] = W[f][kk - (f&7)][n] when (f&7) <= kk < (f&7)+64, else 0.
// (The per-fold shift bakes the window's odd start into the weight layout so the
//  main kernel's x reads start at f & ~7 -> every dwordx4 is 16B-aligned.)
__global__ void transpose_w(const float* __restrict__ w, bf16* __restrict__ wt) {
    __shared__ bf16 lds[2][32][KPAD];                 // 12288 B
    const int t  = threadIdx.x;
    const int f0 = blockIdx.x * 2;

    // zero LDS (pad slots must be 0)
    {
        uint4* z = reinterpret_cast<uint4*>(&lds[0][0][0]);
        const uint4 zz = {0, 0, 0, 0};
        z[t] = zz; z[t + 256] = zz; z[t + 512] = zz;   // 768 * 16B = 12288 B
    }
    __syncthreads();

    // stage + transpose + shift: thread covers 16 f32 of one fold
    {
        const int fp  = t >> 7;                        // fold-in-block 0/1
        const int tt  = t & 127;
        const int shf = (f0 + fp) & 7;
        const float* src = w + (size_t)(f0 + fp) * 2048 + tt * 16;
        #pragma unroll
        for (int v = 0; v < 4; ++v) {
            const float4 val = *reinterpret_cast<const float4*>(src + v * 4);
            const int e  = tt * 16 + v * 4;            // flat elem, n fastest
            const int k  = e >> 5;
            const int n0 = e & 31;
            lds[fp][n0 + 0][k + shf] = __float2bfloat16(val.x);
            lds[fp][n0 + 1][k + shf] = __float2bfloat16(val.y);
            lds[fp][n0 + 2][k + shf] = __float2bfloat16(val.z);
            lds[fp][n0 + 3][k + shf] = __float2bfloat16(val.w);
        }
    }
    __syncthreads();

    // write out coalesced: 192 threads, 64B per thread
    if (t < 192) {
        const int fp = t / 96;
        const int tt = t - fp * 96;
        const int n  = tt / 3;
        const int k0 = (tt - n * 3) * 32;
        const uint4* lp = reinterpret_cast<const uint4*>(&lds[fp][n][k0]);  // 16B-aligned
        uint4* gp = reinterpret_cast<uint4*>(wt + ((size_t)(f0 + fp) * 32 + n) * KPAD + k0);
        gp[0] = lp[0]; gp[1] = lp[1]; gp[2] = lp[2]; gp[3] = lp[3];
    }
}

// ---------- main: no LDS, no barriers; wave = (fold, 32 batch rows) ----------
// D = Wt(32n x 96k) * Xwin^T(96k x 32b); lane regs = 4 consecutive n -> dwordx4 stores.
__global__ __launch_bounds__(256, 4)
void local_linear_main(const bf16* __restrict__ xb, const bf16* __restrict__ wt,
                       const float* __restrict__ bias, float* __restrict__ out)
{
    const int bid  = blockIdx.x;                       // 8192
    const int t    = threadIdx.x;
    const int lane = t & 63;
    const int wid  = t >> 6;

    // XCD-friendly decode: the 8 b-tiles of one fold-group share idx%8 (same XCD)
    const int fgrp  = (bid & 7) * 128 + (bid >> 6);    // 0..1023
    const int btile = (bid >> 3) & 7;                  // 0..7

    const int f     = fgrp * 4 + wid;                  // one fold per wave
    const int base8 = f & ~7;
    const int lrow  = lane & 15;
    const int kgrp  = lane >> 4;
    const int b0    = btile * 32;

    // A-frags: Wt[f][n = mt*16+lrow][ks*32 + kgrp*8 ..+8]
    const bf16* wbase = wt + (size_t)f * (32 * KPAD) + kgrp * 8;
    bf16x8 afr[2][3];
    #pragma unroll
    for (int mt = 0; mt < 2; ++mt)
        #pragma unroll
        for (int ks = 0; ks < 3; ++ks)
            afr[mt][ks] = *reinterpret_cast<const bf16x8*>(
                wbase + (mt * 16 + lrow) * KPAD + ks * 32);

    // B-frags: xb[b0 + bt*16 + lrow][base8 + ks*32 + kgrp*8 ..+8]
    const bf16* xbase = xb + base8 + kgrp * 8;
    bf16x8 bfr[2][3];
    #pragma unroll
    for (int bt = 0; bt < 2; ++bt)
        #pragma unroll
        for (int ks = 0; ks < 3; ++ks)
            bfr[bt][ks] = *reinterpret_cast<const bf16x8*>(
                xbase + (size_t)(b0 + bt * 16 + lrow) * XROW + ks * 32);

    f32x4 acc[2][2];
    #pragma unroll
    for (int mt = 0; mt < 2; ++mt)
        #pragma unroll
        for (int bt = 0; bt < 2; ++bt)
            acc[mt][bt] = (f32x4){0.f, 0.f, 0.f, 0.f};

    #pragma unroll
    for (int ks = 0; ks < 3; ++ks)
        #pragma unroll
        for (int mt = 0; mt < 2; ++mt)
            #pragma unroll
            for (int bt = 0; bt < 2; ++bt)
                acc[mt][bt] = __builtin_amdgcn_mfma_f32_16x16x32_bf16(
                    afr[mt][ks], bfr[bt][ks], acc[mt][bt], 0, 0, 0);

    // epilogue: lane holds n = mt*16 + kgrp*4 + r (4 consecutive), b = b0+bt*16+lrow
    #pragma unroll
    for (int mt = 0; mt < 2; ++mt) {
        const float4 bv = *reinterpret_cast<const float4*>(
            bias + f * 32 + mt * 16 + kgrp * 4);
        #pragma unroll
        for (int bt = 0; bt < 2; ++bt) {
            const size_t b = b0 + bt * 16 + lrow;
            float4 o;
            o.x = acc[mt][bt][0] + bv.x;
            o.y = acc[mt][bt][1] + bv.y;
            o.z = acc[mt][bt][2] + bv.z;
            o.w = acc[mt][bt][3] + bv.w;
            *reinterpret_cast<float4*>(
                out + (b * FOLD_NUM + f) * 32 + mt * 16 + kgrp * 4) = o;
        }
    }
}

// ---------- fallback (round-2 kernel, known-passing) ----------
#define LDA 80
#define LDB 80
__global__ __launch_bounds__(256, 2)
void local_linear_kernel(const float* __restrict__ x, const float* __restrict__ w,
                         const float* __restrict__ bias, float* __restrict__ out)
{
    __shared__ bf16 As[BATCH * LDA];
    __shared__ bf16 Bs[LOCAL_FEATURES * LDB];
    const int f = blockIdx.x, t = threadIdx.x, lane = t & 63, wid = t >> 6;
    {
        const int col = lane, gcol = f + col;
        const bool valid = (gcol < IN_FEATURES);
        const float* xp = x + gcol;
        #pragma unroll 8
        for (int i = 0; i < 64; ++i) {
            const int row = wid + i * 4;
            float v = valid ? xp[(size_t)row * IN_FEATURES] : 0.0f;
            As[row * LDA + col] = __float2bfloat16(v);
        }
    }
    {
        const float* wf = w + (size_t)f * (KERNEL_SIZE * LOCAL_FEATURES);
        #pragma unroll
        for (int v4 = 0; v4 < 2; ++v4) {
            const int e0 = (t + v4 * 256) * 4;
            const float4 val = *reinterpret_cast<const float4*>(wf + e0);
            const int k = e0 >> 5, n = e0 & 31;
            Bs[(n + 0) * LDB + k] = __float2bfloat16(val.x);
            Bs[(n + 1) * LDB + k] = __float2bfloat16(val.y);
            Bs[(n + 2) * LDB + k] = __float2bfloat16(val.z);
            Bs[(n + 3) * LDB + k] = __float2bfloat16(val.w);
        }
    }
    __syncthreads();
    f32x4 acc[4][2];
    #pragma unroll
    for (int mt = 0; mt < 4; ++mt)
        #pragma unroll
        for (int nt = 0; nt < 2; ++nt) acc[mt][nt] = (f32x4){0.f,0.f,0.f,0.f};
    const int lrow = lane & 15, kgrp = lane >> 4;
    #pragma unroll
    for (int ks = 0; ks < 2; ++ks) {
        const int kbase = ks * 32 + kgrp * 8;
        bf16x8 bfrag[2], afrag[4];
        #pragma unroll
        for (int nt = 0; nt < 2; ++nt)
            bfrag[nt] = *reinterpret_cast<const bf16x8*>(&Bs[(nt*16+lrow) * LDB + kbase]);
        #pragma unroll
        for (int mt = 0; mt < 4; ++mt)
            afrag[mt] = *reinterpret_cast<const bf16x8*>(&As[(wid*64+mt*16+lrow) * LDA + kbase]);
        #pragma unroll
        for (int mt = 0; mt < 4; ++mt)
            #pragma unroll
            for (int nt = 0; nt < 2; ++nt)
                acc[mt][nt] = __builtin_amdgcn_mfma_f32_16x16x32_bf16(
                    afrag[mt], bfrag[nt], acc[mt][nt], 0, 0, 0);
    }
    float bv[2];
    bv[0] = bias[f * 32 + lrow];
    bv[1] = bias[f * 32 + 16 + lrow];
    #pragma unroll
    for (int mt = 0; mt < 4; ++mt)
        #pragma unroll
        for (int nt = 0; nt < 2; ++nt) {
            const int n = nt * 16 + lrow;
            #pragma unroll
            for (int r = 0; r < 4; ++r) {
                const int b = wid * 64 + mt * 16 + kgrp * 4 + r;
                out[((size_t)b * FOLD_NUM + f) * 32 + n] = acc[mt][nt][r] + bv[nt];
            }
        }
}

extern "C" void kernel_launch(void* const* d_in, const int* in_sizes, int n_in,
                              void* d_out, int out_size, void* d_ws, size_t ws_size,
                              hipStream_t stream) {
    const float* x    = (const float*)d_in[0];
    const float* wgt  = (const float*)d_in[1];
    const float* bias = (const float*)d_in[2];
    float* out        = (float*)d_out;

    const size_t WS_X = (size_t)BATCH * XROW * sizeof(bf16);          // 2,146,304 B
    const size_t WS_W = (size_t)FOLD_NUM * 32 * KPAD * sizeof(bf16);  // 25,165,824 B

    if (ws_size >= WS_X + WS_W) {
        bf16* xb = (bf16*)d_ws;
        bf16* wt = (bf16*)((char*)d_ws + WS_X);
        convert_pad_x<<<524, 256, 0, stream>>>(x, xb);
        transpose_w<<<FOLD_NUM / 2, 256, 0, stream>>>(wgt, wt);
        local_linear_main<<<8192, 256, 0, stream>>>(xb, wt, bias, out);
    } else {
        local_linear_kernel<<<FOLD_NUM, 256, 0, stream>>>(x, wgt, bias, out);
    }
}

// Round 6
// 193.629 us; speedup vs baseline: 1.5966x; 1.0486x over previous
//
#include <hip/hip_runtime.h>
#include <hip/hip_bf16.h>

#define IN_FEATURES   4096
#define LOCAL_FEATURES  32
#define KERNEL_SIZE     64
#define FOLD_NUM      4096
#define BATCH          256

// padded geometry for aligned loads
#define XROW 4192               // 4096 + 96 pad (bf16 elems), row stride 8384 B (16B-mult)
#define KPAD 96                 // K padded 64 -> 96: slot base (f & ~7) keeps 16B alignment

using bf16 = __hip_bfloat16;
typedef __attribute__((ext_vector_type(8))) short bf16x8;
typedef __attribute__((ext_vector_type(4))) float f32x4;

static __device__ __forceinline__ short bfbits(float v) {
    __hip_bfloat16 h = __float2bfloat16(v);
    return *reinterpret_cast<short*>(&h);
}

// ---------- fused prep: bid<2048 -> weight transpose (2 folds/block);
//                        bid>=2048 -> x convert+pad ----------
// wt[f][n][kk] = W[f][kk - (f&7)][n] for (f&7) <= kk < (f&7)+64, else 0.
__global__ void prep_kernel(const float* __restrict__ x, const float* __restrict__ w,
                            bf16* __restrict__ xb, bf16* __restrict__ wt) {
    __shared__ bf16 lds[2][32][KPAD];                  // 12288 B
    const int t = threadIdx.x;

    if (blockIdx.x >= 2048) {
        // ---- convert x f32 [256][4096] -> bf16 [256][4192], zero pad ----
        const int u   = (blockIdx.x - 2048) * 256 + t; // 134144 = 524*256 vec8 units
        const int row = u / 524;
        const int c8  = (u - row * 524) * 8;
        bf16x8 o;
        if (c8 < 4096) {
            const float4 a = *reinterpret_cast<const float4*>(x + (size_t)row * 4096 + c8);
            const float4 b = *reinterpret_cast<const float4*>(x + (size_t)row * 4096 + c8 + 4);
            o[0] = bfbits(a.x); o[1] = bfbits(a.y); o[2] = bfbits(a.z); o[3] = bfbits(a.w);
            o[4] = bfbits(b.x); o[5] = bfbits(b.y); o[6] = bfbits(b.z); o[7] = bfbits(b.w);
        } else {
            o = (bf16x8){0,0,0,0,0,0,0,0};
        }
        *reinterpret_cast<bf16x8*>(xb + (size_t)row * XROW + c8) = o;
        return;
    }

    // ---- weight transpose+shift for folds f0, f0+1 ----
    const int f0 = blockIdx.x * 2;
    {
        uint4* z = reinterpret_cast<uint4*>(&lds[0][0][0]);
        const uint4 zz = {0, 0, 0, 0};
        z[t] = zz; z[t + 256] = zz; z[t + 512] = zz;   // 768 * 16B = 12288 B
    }
    __syncthreads();
    {
        const int fp  = t >> 7;                        // fold-in-block 0/1
        const int tt  = t & 127;
        const int shf = (f0 + fp) & 7;
        const float* src = w + (size_t)(f0 + fp) * 2048 + tt * 16;
        #pragma unroll
        for (int v = 0; v < 4; ++v) {
            const float4 val = *reinterpret_cast<const float4*>(src + v * 4);
            const int e  = tt * 16 + v * 4;            // flat elem, n fastest
            const int k  = e >> 5;
            const int n0 = e & 31;
            lds[fp][n0 + 0][k + shf] = __float2bfloat16(val.x);
            lds[fp][n0 + 1][k + shf] = __float2bfloat16(val.y);
            lds[fp][n0 + 2][k + shf] = __float2bfloat16(val.z);
            lds[fp][n0 + 3][k + shf] = __float2bfloat16(val.w);
        }
    }
    __syncthreads();
    if (t < 192) {
        const int fp = t / 96;
        const int tt = t - fp * 96;
        const int n  = tt / 3;
        const int k0 = (tt - n * 3) * 32;
        const uint4* lp = reinterpret_cast<const uint4*>(&lds[fp][n][k0]);
        uint4* gp = reinterpret_cast<uint4*>(wt + ((size_t)(f0 + fp) * 32 + n) * KPAD + k0);
        gp[0] = lp[0]; gp[1] = lp[1]; gp[2] = lp[2]; gp[3] = lp[3];
    }
}

// ---------- main: block = 16 folds x 32 batch rows; wave = 4 folds x 32 rows ----------
// The wave's 4 folds share base8 -> shared B-frags (x), 2KB-contiguous write spans.
__global__ __launch_bounds__(256, 2)
void local_linear_main(const bf16* __restrict__ xb, const bf16* __restrict__ wt,
                       const float* __restrict__ bias, float* __restrict__ out)
{
    const int bid   = blockIdx.x;            // 2048
    const int t     = threadIdx.x;
    const int lane  = t & 63;
    const int wid   = t >> 6;

    // 8 b-tiles of one f-tile share bid%8 -> same XCD L2 for wt reuse
    const int ftile = bid & 255;
    const int btile = bid >> 8;              // 0..7
    const int f0    = ftile * 16;
    const int fw    = f0 + wid * 4;          // wave's first fold (4 consecutive)
    const int base8 = fw & ~7;               // shared aligned x-window base
    const int lrow  = lane & 15;
    const int kgrp  = lane >> 4;
    const int b0    = btile * 32;

    // B-frags (x window), shared across the wave's 4 folds: 6 x 16B loads
    bf16x8 bfr[2][3];
    {
        const bf16* xbase = xb + base8 + kgrp * 8;
        #pragma unroll
        for (int bt = 0; bt < 2; ++bt)
            #pragma unroll
            for (int ks = 0; ks < 3; ++ks)
                bfr[bt][ks] = *reinterpret_cast<const bf16x8*>(
                    xbase + (size_t)(b0 + bt * 16 + lrow) * XROW + ks * 32);
    }

    f32x4 acc[4][2][2];
    #pragma unroll
    for (int i = 0; i < 4; ++i)
        #pragma unroll
        for (int mt = 0; mt < 2; ++mt)
            #pragma unroll
            for (int bt = 0; bt < 2; ++bt)
                acc[i][mt][bt] = (f32x4){0.f, 0.f, 0.f, 0.f};

    #pragma unroll
    for (int i = 0; i < 4; ++i) {
        const bf16* wbase = wt + (size_t)(fw + i) * (32 * KPAD) + kgrp * 8;
        bf16x8 afr[2][3];
        #pragma unroll
        for (int mt = 0; mt < 2; ++mt)
            #pragma unroll
            for (int ks = 0; ks < 3; ++ks)
                afr[mt][ks] = *reinterpret_cast<const bf16x8*>(
                    wbase + (mt * 16 + lrow) * KPAD + ks * 32);
        #pragma unroll
        for (int ks = 0; ks < 3; ++ks)
            #pragma unroll
            for (int mt = 0; mt < 2; ++mt)
                #pragma unroll
                for (int bt = 0; bt < 2; ++bt)
                    acc[i][mt][bt] = __builtin_amdgcn_mfma_f32_16x16x32_bf16(
                        afr[mt][ks], bfr[bt][ks], acc[i][mt][bt], 0, 0, 0);
    }

    // epilogue: lane holds n = mt*16 + kgrp*4 + r, b = b0 + bt*16 + lrow
    #pragma unroll
    for (int i = 0; i < 4; ++i) {
        const int f = fw + i;
        #pragma unroll
        for (int mt = 0; mt < 2; ++mt) {
            const float4 bv = *reinterpret_cast<const float4*>(
                bias + f * 32 + mt * 16 + kgrp * 4);
            #pragma unroll
            for (int bt = 0; bt < 2; ++bt) {
                const size_t b = b0 + bt * 16 + lrow;
                float4 o;
                o.x = acc[i][mt][bt][0] + bv.x;
                o.y = acc[i][mt][bt][1] + bv.y;
                o.z = acc[i][mt][bt][2] + bv.z;
                o.w = acc[i][mt][bt][3] + bv.w;
                *reinterpret_cast<float4*>(
                    out + (b * FOLD_NUM + f) * 32 + mt * 16 + kgrp * 4) = o;
            }
        }
    }
}

// ---------- fallback (round-2 kernel, known-passing) ----------
#define LDA 80
#define LDB 80
__global__ __launch_bounds__(256, 2)
void local_linear_kernel(const float* __restrict__ x, const float* __restrict__ w,
                         const float* __restrict__ bias, float* __restrict__ out)
{
    __shared__ bf16 As[BATCH * LDA];
    __shared__ bf16 Bs[LOCAL_FEATURES * LDB];
    const int f = blockIdx.x, t = threadIdx.x, lane = t & 63, wid = t >> 6;
    {
        const int col = lane, gcol = f + col;
        const bool valid = (gcol < IN_FEATURES);
        const float* xp = x + gcol;
        #pragma unroll 8
        for (int i = 0; i < 64; ++i) {
            const int row = wid + i * 4;
            float v = valid ? xp[(size_t)row * IN_FEATURES] : 0.0f;
            As[row * LDA + col] = __float2bfloat16(v);
        }
    }
    {
        const float* wf = w + (size_t)f * (KERNEL_SIZE * LOCAL_FEATURES);
        #pragma unroll
        for (int v4 = 0; v4 < 2; ++v4) {
            const int e0 = (t + v4 * 256) * 4;
            const float4 val = *reinterpret_cast<const float4*>(wf + e0);
            const int k = e0 >> 5, n = e0 & 31;
            Bs[(n + 0) * LDB + k] = __float2bfloat16(val.x);
            Bs[(n + 1) * LDB + k] = __float2bfloat16(val.y);
            Bs[(n + 2) * LDB + k] = __float2bfloat16(val.z);
            Bs[(n + 3) * LDB + k] = __float2bfloat16(val.w);
        }
    }
    __syncthreads();
    f32x4 acc[4][2];
    #pragma unroll
    for (int mt = 0; mt < 4; ++mt)
        #pragma unroll
        for (int nt = 0; nt < 2; ++nt) acc[mt][nt] = (f32x4){0.f,0.f,0.f,0.f};
    const int lrow = lane & 15, kgrp = lane >> 4;
    #pragma unroll
    for (int ks = 0; ks < 2; ++ks) {
        const int kbase = ks * 32 + kgrp * 8;
        bf16x8 bfrag[2], afrag[4];
        #pragma unroll
        for (int nt = 0; nt < 2; ++nt)
            bfrag[nt] = *reinterpret_cast<const bf16x8*>(&Bs[(nt*16+lrow) * LDB + kbase]);
        #pragma unroll
        for (int mt = 0; mt < 4; ++mt)
            afrag[mt] = *reinterpret_cast<const bf16x8*>(&As[(wid*64+mt*16+lrow) * LDA + kbase]);
        #pragma unroll
        for (int mt = 0; mt < 4; ++mt)
            #pragma unroll
            for (int nt = 0; nt < 2; ++nt)
                acc[mt][nt] = __builtin_amdgcn_mfma_f32_16x16x32_bf16(
                    afrag[mt], bfrag[nt], acc[mt][nt], 0, 0, 0);
    }
    float bv[2];
    bv[0] = bias[f * 32 + lrow];
    bv[1] = bias[f * 32 + 16 + lrow];
    #pragma unroll
    for (int mt = 0; mt < 4; ++mt)
        #pragma unroll
        for (int nt = 0; nt < 2; ++nt) {
            const int n = nt * 16 + lrow;
            #pragma unroll
            for (int r = 0; r < 4; ++r) {
                const int b = wid * 64 + mt * 16 + kgrp * 4 + r;
                out[((size_t)b * FOLD_NUM + f) * 32 + n] = acc[mt][nt][r] + bv[nt];
            }
        }
}

extern "C" void kernel_launch(void* const* d_in, const int* in_sizes, int n_in,
                              void* d_out, int out_size, void* d_ws, size_t ws_size,
                              hipStream_t stream) {
    const float* x    = (const float*)d_in[0];
    const float* wgt  = (const float*)d_in[1];
    const float* bias = (const float*)d_in[2];
    float* out        = (float*)d_out;

    const size_t WS_X = (size_t)BATCH * XROW * sizeof(bf16);          // 2,146,304 B
    const size_t WS_W = (size_t)FOLD_NUM * 32 * KPAD * sizeof(bf16);  // 25,165,824 B

    if (ws_size >= WS_X + WS_W) {
        bf16* xb = (bf16*)d_ws;
        bf16* wt = (bf16*)((char*)d_ws + WS_X);
        prep_kernel<<<2048 + 524, 256, 0, stream>>>(x, wgt, xb, wt);
        local_linear_main<<<2048, 256, 0, stream>>>(xb, wt, bias, out);
    } else {
        local_linear_kernel<<<FOLD_NUM, 256, 0, stream>>>(x, wgt, bias, out);
    }
}

// Round 7
// 185.027 us; speedup vs baseline: 1.6708x; 1.0465x over previous
//
#include <hip/hip_runtime.h>
#include <hip/hip_bf16.h>

#define IN_FEATURES   4096
#define LOCAL_FEATURES  32
#define KERNEL_SIZE     64
#define FOLD_NUM      4096
#define BATCH          256

// padded geometry for aligned loads
#define XROW 4192               // 4096 + 96 pad (bf16 elems), row stride 8384 B (16B-mult)
#define KPAD 96                 // K padded 64 -> 96: slot base (f & ~7) keeps 16B alignment
#define EROW 520                // epilogue LDS row stride in f32 (512 + 8 pad)

using bf16 = __hip_bfloat16;
typedef __attribute__((ext_vector_type(8))) short bf16x8;
typedef __attribute__((ext_vector_type(4))) float f32x4;

static __device__ __forceinline__ short bfbits(float v) {
    __hip_bfloat16 h = __float2bfloat16(v);
    return *reinterpret_cast<short*>(&h);
}

// ---------- fused prep: bid<2048 -> weight transpose (2 folds/block);
//                        bid>=2048 -> x convert+pad ----------
// wt[f][n][kk] = W[f][kk - (f&7)][n] for (f&7) <= kk < (f&7)+64, else 0.
__global__ void prep_kernel(const float* __restrict__ x, const float* __restrict__ w,
                            bf16* __restrict__ xb, bf16* __restrict__ wt) {
    __shared__ bf16 lds[2][32][KPAD];                  // 12288 B
    const int t = threadIdx.x;

    if (blockIdx.x >= 2048) {
        // ---- convert x f32 [256][4096] -> bf16 [256][4192], zero pad ----
        const int u   = (blockIdx.x - 2048) * 256 + t; // 134144 = 524*256 vec8 units
        const int row = u / 524;
        const int c8  = (u - row * 524) * 8;
        bf16x8 o;
        if (c8 < 4096) {
            const float4 a = *reinterpret_cast<const float4*>(x + (size_t)row * 4096 + c8);
            const float4 b = *reinterpret_cast<const float4*>(x + (size_t)row * 4096 + c8 + 4);
            o[0] = bfbits(a.x); o[1] = bfbits(a.y); o[2] = bfbits(a.z); o[3] = bfbits(a.w);
            o[4] = bfbits(b.x); o[5] = bfbits(b.y); o[6] = bfbits(b.z); o[7] = bfbits(b.w);
        } else {
            o = (bf16x8){0,0,0,0,0,0,0,0};
        }
        *reinterpret_cast<bf16x8*>(xb + (size_t)row * XROW + c8) = o;
        return;
    }

    // ---- weight transpose+shift for folds f0, f0+1 ----
    const int f0 = blockIdx.x * 2;
    {
        uint4* z = reinterpret_cast<uint4*>(&lds[0][0][0]);
        const uint4 zz = {0, 0, 0, 0};
        z[t] = zz; z[t + 256] = zz; z[t + 512] = zz;   // 768 * 16B = 12288 B
    }
    __syncthreads();
    {
        const int fp  = t >> 7;                        // fold-in-block 0/1
        const int tt  = t & 127;
        const int shf = (f0 + fp) & 7;
        const float* src = w + (size_t)(f0 + fp) * 2048 + tt * 16;
        #pragma unroll
        for (int v = 0; v < 4; ++v) {
            const float4 val = *reinterpret_cast<const float4*>(src + v * 4);
            const int e  = tt * 16 + v * 4;            // flat elem, n fastest
            const int k  = e >> 5;
            const int n0 = e & 31;
            lds[fp][n0 + 0][k + shf] = __float2bfloat16(val.x);
            lds[fp][n0 + 1][k + shf] = __float2bfloat16(val.y);
            lds[fp][n0 + 2][k + shf] = __float2bfloat16(val.z);
            lds[fp][n0 + 3][k + shf] = __float2bfloat16(val.w);
        }
    }
    __syncthreads();
    if (t < 192) {
        const int fp = t / 96;
        const int tt = t - fp * 96;
        const int n  = tt / 3;
        const int k0 = (tt - n * 3) * 32;
        const uint4* lp = reinterpret_cast<const uint4*>(&lds[fp][n][k0]);
        uint4* gp = reinterpret_cast<uint4*>(wt + ((size_t)(f0 + fp) * 32 + n) * KPAD + k0);
        gp[0] = lp[0]; gp[1] = lp[1]; gp[2] = lp[2]; gp[3] = lp[3];
    }
}

// ---------- main: block = 16 folds x 32 batch rows; wave = 4 folds x 32 rows ----------
// LDS-staged epilogue: acc -> LDS -> 1KB-contiguous nontemporal dwordx4 streams.
__global__ __launch_bounds__(256, 2)
void local_linear_main(const bf16* __restrict__ xb, const bf16* __restrict__ wt,
                       const float* __restrict__ bias, float* __restrict__ out)
{
    __shared__ float eld[16 * EROW];         // 33280 B, one bt-half at a time

    const int bid   = blockIdx.x;            // 2048
    const int t     = threadIdx.x;
    const int lane  = t & 63;
    const int wid   = t >> 6;

    // 8 b-tiles of one f-tile share bid%8 -> same XCD L2 for wt reuse
    const int ftile = bid & 255;
    const int btile = bid >> 8;              // 0..7
    const int f0    = ftile * 16;
    const int fw    = f0 + wid * 4;          // wave's first fold (4 consecutive)
    const int base8 = fw & ~7;               // shared aligned x-window base
    const int lrow  = lane & 15;
    const int kgrp  = lane >> 4;
    const int b0    = btile * 32;

    // B-frags (x window), shared across the wave's 4 folds: 6 x 16B loads
    bf16x8 bfr[2][3];
    {
        const bf16* xbase = xb + base8 + kgrp * 8;
        #pragma unroll
        for (int bt = 0; bt < 2; ++bt)
            #pragma unroll
            for (int ks = 0; ks < 3; ++ks)
                bfr[bt][ks] = *reinterpret_cast<const bf16x8*>(
                    xbase + (size_t)(b0 + bt * 16 + lrow) * XROW + ks * 32);
    }

    f32x4 acc[4][2][2];
    #pragma unroll
    for (int i = 0; i < 4; ++i)
        #pragma unroll
        for (int mt = 0; mt < 2; ++mt)
            #pragma unroll
            for (int bt = 0; bt < 2; ++bt)
                acc[i][mt][bt] = (f32x4){0.f, 0.f, 0.f, 0.f};

    #pragma unroll
    for (int i = 0; i < 4; ++i) {
        const bf16* wbase = wt + (size_t)(fw + i) * (32 * KPAD) + kgrp * 8;
        bf16x8 afr[2][3];
        #pragma unroll
        for (int mt = 0; mt < 2; ++mt)
            #pragma unroll
            for (int ks = 0; ks < 3; ++ks)
                afr[mt][ks] = *reinterpret_cast<const bf16x8*>(
                    wbase + (mt * 16 + lrow) * KPAD + ks * 32);
        #pragma unroll
        for (int ks = 0; ks < 3; ++ks)
            #pragma unroll
            for (int mt = 0; mt < 2; ++mt)
                #pragma unroll
                for (int bt = 0; bt < 2; ++bt)
                    acc[i][mt][bt] = __builtin_amdgcn_mfma_f32_16x16x32_bf16(
                        afr[mt][ks], bfr[bt][ks], acc[i][mt][bt], 0, 0, 0);
    }

    // preload bias (per-lane n = mt*16 + kgrp*4 .. +3 for each of the 4 folds)
    float4 bv[4][2];
    #pragma unroll
    for (int i = 0; i < 4; ++i)
        #pragma unroll
        for (int mt = 0; mt < 2; ++mt)
            bv[i][mt] = *reinterpret_cast<const float4*>(
                bias + (fw + i) * 32 + mt * 16 + kgrp * 4);

    // ---- epilogue: two bt-halves through LDS, then contiguous streams ----
    const size_t gbase = (size_t)b0 * (FOLD_NUM * 32) + (size_t)f0 * 32;

    #pragma unroll
    for (int bt = 0; bt < 2; ++bt) {
        if (bt) __syncthreads();             // protect eld reuse
        // stage 1: acc (+bias) -> LDS [brow16 = lrow][fold*32 + n]
        #pragma unroll
        for (int i = 0; i < 4; ++i) {
            const int fold = wid * 4 + i;
            #pragma unroll
            for (int mt = 0; mt < 2; ++mt) {
                f32x4 o = acc[i][mt][bt];
                o[0] += bv[i][mt].x; o[1] += bv[i][mt].y;
                o[2] += bv[i][mt].z; o[3] += bv[i][mt].w;
                *reinterpret_cast<f32x4*>(
                    &eld[lrow * EROW + fold * 32 + mt * 16 + kgrp * 4]) = o;
            }
        }
        __syncthreads();
        // stage 2: LDS -> global, 1KB contiguous per instruction
        #pragma unroll
        for (int j = 0; j < 8; ++j) {
            const int Lf    = (wid * 8 + j) * 256 + lane * 4;  // f32 index in half (0..8191)
            const int brow16 = Lf >> 9;                        // 0..15
            const int r      = Lf & 511;                       // within-row f32 offset
            const f32x4 v = *reinterpret_cast<const f32x4*>(&eld[brow16 * EROW + r]);
            const size_t g = gbase + (size_t)(bt * 16 + brow16) * (FOLD_NUM * 32) + r;
            __builtin_nontemporal_store(v, reinterpret_cast<f32x4*>(out + g));
        }
    }
}

// ---------- fallback (round-2 kernel, known-passing) ----------
#define LDA 80
#define LDB 80
__global__ __launch_bounds__(256, 2)
void local_linear_kernel(const float* __restrict__ x, const float* __restrict__ w,
                         const float* __restrict__ bias, float* __restrict__ out)
{
    __shared__ bf16 As[BATCH * LDA];
    __shared__ bf16 Bs[LOCAL_FEATURES * LDB];
    const int f = blockIdx.x, t = threadIdx.x, lane = t & 63, wid = t >> 6;
    {
        const int col = lane, gcol = f + col;
        const bool valid = (gcol < IN_FEATURES);
        const float* xp = x + gcol;
        #pragma unroll 8
        for (int i = 0; i < 64; ++i) {
            const int row = wid + i * 4;
            float v = valid ? xp[(size_t)row * IN_FEATURES] : 0.0f;
            As[row * LDA + col] = __float2bfloat16(v);
        }
    }
    {
        const float* wf = w + (size_t)f * (KERNEL_SIZE * LOCAL_FEATURES);
        #pragma unroll
        for (int v4 = 0; v4 < 2; ++v4) {
            const int e0 = (t + v4 * 256) * 4;
            const float4 val = *reinterpret_cast<const float4*>(wf + e0);
            const int k = e0 >> 5, n = e0 & 31;
            Bs[(n + 0) * LDB + k] = __float2bfloat16(val.x);
            Bs[(n + 1) * LDB + k] = __float2bfloat16(val.y);
            Bs[(n + 2) * LDB + k] = __float2bfloat16(val.z);
            Bs[(n + 3) * LDB + k] = __float2bfloat16(val.w);
        }
    }
    __syncthreads();
    f32x4 acc[4][2];
    #pragma unroll
    for (int mt = 0; mt < 4; ++mt)
        #pragma unroll
        for (int nt = 0; nt < 2; ++nt) acc[mt][nt] = (f32x4){0.f,0.f,0.f,0.f};
    const int lrow = lane & 15, kgrp = lane >> 4;
    #pragma unroll
    for (int ks = 0; ks < 2; ++ks) {
        const int kbase = ks * 32 + kgrp * 8;
        bf16x8 bfrag[2], afrag[4];
        #pragma unroll
        for (int nt = 0; nt < 2; ++nt)
            bfrag[nt] = *reinterpret_cast<const bf16x8*>(&Bs[(nt*16+lrow) * LDB + kbase]);
        #pragma unroll
        for (int mt = 0; mt < 4; ++mt)
            afrag[mt] = *reinterpret_cast<const bf16x8*>(&As[(wid*64+mt*16+lrow) * LDA + kbase]);
        #pragma unroll
        for (int mt = 0; mt < 4; ++mt)
            #pragma unroll
            for (int nt = 0; nt < 2; ++nt)
                acc[mt][nt] = __builtin_amdgcn_mfma_f32_16x16x32_bf16(
                    afrag[mt], bfrag[nt], acc[mt][nt], 0, 0, 0);
    }
    float bv[2];
    bv[0] = bias[f * 32 + lrow];
    bv[1] = bias[f * 32 + 16 + lrow];
    #pragma unroll
    for (int mt = 0; mt < 4; ++mt)
        #pragma unroll
        for (int nt = 0; nt < 2; ++nt) {
            const int n = nt * 16 + lrow;
            #pragma unroll
            for (int r = 0; r < 4; ++r) {
                const int b = wid * 64 + mt * 16 + kgrp * 4 + r;
                out[((size_t)b * FOLD_NUM + f) * 32 + n] = acc[mt][nt][r] + bv[nt];
            }
        }
}

extern "C" void kernel_launch(void* const* d_in, const int* in_sizes, int n_in,
                              void* d_out, int out_size, void* d_ws, size_t ws_size,
                              hipStream_t stream) {
    const float* x    = (const float*)d_in[0];
    const float* wgt  = (const float*)d_in[1];
    const float* bias = (const float*)d_in[2];
    float* out        = (float*)d_out;

    const size_t WS_X = (size_t)BATCH * XROW * sizeof(bf16);          // 2,146,304 B
    const size_t WS_W = (size_t)FOLD_NUM * 32 * KPAD * sizeof(bf16);  // 25,165,824 B

    if (ws_size >= WS_X + WS_W) {
        bf16* xb = (bf16*)d_ws;
        bf16* wt = (bf16*)((char*)d_ws + WS_X);
        prep_kernel<<<2048 + 524, 256, 0, stream>>>(x, wgt, xb, wt);
        local_linear_main<<<2048, 256, 0, stream>>>(xb, wt, bias, out);
    } else {
        local_linear_kernel<<<FOLD_NUM, 256, 0, stream>>>(x, wgt, bias, out);
    }
}